// Round 2
// baseline (257.321 us; speedup 1.0000x reference)
//
#include <hip/hip_runtime.h>

#define IPB 20        // items per block (500 of 512 lanes active)
#define NT 512
#define NQ 25
#define KVD 9
#define QSCALE 0.4808983469629878f      /* log2(e)/3 : folds 1/sqrt(9) and exp->exp2 */
#define MSCALE (-1.4426950408889634e9f) /* -1e9 * log2(e) */

// dot of 8 floats from LDS (two b128) against xv[0..7], seeded
__device__ __forceinline__ float dot8(const float* __restrict__ w,
                                      const float* __restrict__ xv, float acc) {
  float4 a = *(const float4*)(w);
  float4 b = *(const float4*)(w + 4);
  acc = fmaf(a.x, xv[0], acc);
  acc = fmaf(a.y, xv[1], acc);
  acc = fmaf(a.z, xv[2], acc);
  acc = fmaf(a.w, xv[3], acc);
  acc = fmaf(b.x, xv[4], acc);
  acc = fmaf(b.y, xv[5], acc);
  acc = fmaf(b.z, xv[6], acc);
  acc = fmaf(b.w, xv[7], acc);
  return acc;
}

// 9-dim projection. w9/bias are stride-9 scalar LDS arrays (broadcast b32 reads,
// immediate offsets) -- saves 288 B of LDS to hit the 40960 B / 4-blocks-per-CU cap.
__device__ __forceinline__ void proj9(const float* __restrict__ w8,
                                      const float* __restrict__ w9,
                                      const float* __restrict__ bias,
                                      const float* __restrict__ xv,
                                      float* __restrict__ outv) {
#pragma unroll
  for (int e = 0; e < KVD; ++e)
    outv[e] = dot8(w8 + e * 8, xv, fmaf(w9[e], xv[8], bias[e]));
}

// LDS budget: 3456 + 432 + 432 + 16000 + 2240 + 16000 + 2240 = 40800 B
// -> rounds to 40960 B = exactly 160 KiB / 4 -> 4 blocks/CU x 8 waves
// = 32 waves/CU = 100% occupancy cap (was 6 blocks x 23 KB = 24 waves, 75%).
// launch_bounds(512, 8): 8 waves/EU -> VGPR cap 64; compiler needs ~40.
__global__ __launch_bounds__(NT, 8) void attn_fused(
    const float* __restrict__ x, const float* __restrict__ mask,
    const float* __restrict__ Wq, const float* __restrict__ bq,
    const float* __restrict__ Wk, const float* __restrict__ bk,
    const float* __restrict__ Wv, const float* __restrict__ bv,
    const float* __restrict__ gamma, const float* __restrict__ beta,
    float* __restrict__ out, int B) {
  __shared__ __align__(16) float sW8[3][4][KVD][8];   // 3456 B
  __shared__ __align__(16) float sW9[3][4][KVD];      //  432 B (scalar reads)
  __shared__ __align__(16) float sBias[3][4][KVD];    //  432 B (scalar reads)
  __shared__ __align__(16) float sK8[IPB][NQ][8];     // 16000 B
  __shared__ __align__(16) float sK9[IPB][28];        //  2240 B (112 B rows, 16-aligned)
  __shared__ __align__(16) float sV8[IPB][NQ][8];     // 16000 B
  __shared__ __align__(16) float sV9[IPB][28];        //  2240 B

  const int tid = threadIdx.x;
  const int il = tid / NQ;
  const int tk = tid - il * NQ;
  const long item = (long)blockIdx.x * IPB + il;
  const bool active = (tid < IPB * NQ) && (item < (long)B);

  // ---- prefetch x before staging: HBM latency hides behind weight staging ----
  float xv[KVD];
  if (active) {
    const float* xp = x + item * 225 + tk * KVD;
#pragma unroll
    for (int d = 0; d < KVD; ++d) xv[d] = xp[d];
  }

  // ---- stage parameters: straight-line, one trip (324+36 <= 512 threads) ----
  if (tid < 324) {  // 4*9*9 weights
    int g = tid / 81;
    int r = tid - g * 81;
    int e = r / 9;
    int d = r - e * 9;
    float a = Wq[tid] * QSCALE, b = Wk[tid], c = Wv[tid];
    if (d < 8) {
      sW8[0][g][e][d] = a; sW8[1][g][e][d] = b; sW8[2][g][e][d] = c;
    } else {
      sW9[0][g][e] = a; sW9[1][g][e] = b; sW9[2][g][e] = c;
    }
  } else if (tid < 360) {  // biases staged by the next 36 threads, in parallel
    int i = tid - 324;
    int g = i / 9, d = i - g * 9;
    sBias[0][g][d] = bq[i] * QSCALE;
    sBias[1][g][d] = bk[i];
    sBias[2][g][d] = bv[i];
  }
  __syncthreads();

  const int g = (tk < 3) ? 0 : (tk < 13) ? 1 : (tk < 23) ? 2 : 3;
  if (active) {
    // k and v share one temp array; q is computed after the barrier so its
    // registers don't sit live across the K/V store phase.
    float t[KVD];
    proj9(&sW8[1][g][0][0], &sW9[1][g][0], &sBias[1][g][0], xv, t);
    *(float4*)&sK8[il][tk][0] = make_float4(t[0], t[1], t[2], t[3]);
    *(float4*)&sK8[il][tk][4] = make_float4(t[4], t[5], t[6], t[7]);
    sK9[il][tk] = t[8];
    proj9(&sW8[2][g][0][0], &sW9[2][g][0], &sBias[2][g][0], xv, t);
    *(float4*)&sV8[il][tk][0] = make_float4(t[0], t[1], t[2], t[3]);
    *(float4*)&sV8[il][tk][4] = make_float4(t[4], t[5], t[6], t[7]);
    sV9[il][tk] = t[8];
  }
  __syncthreads();

  if (active) {
    float q[KVD];
    proj9(&sW8[0][g][0][0], &sW9[0][g][0], &sBias[0][g][0], xv, q);

    const float* kb = &sK8[il][0][0];
    const float* k9 = &sK9[il][0];
    const float* vb = &sV8[il][0][0];
    const float* v9 = &sV9[il][0];

    // seed scores with mask: mask[j] is wave-uniform -> s_load, one v_mul each
    float s[NQ];
#pragma unroll
    for (int j = 0; j < NQ; ++j) s[j] = mask[j] * MSCALE;

#pragma unroll
    for (int j = 0; j < NQ; ++j) s[j] = dot8(kb + j * 8, q, s[j]);
    const float q8 = q[8];
#pragma unroll
    for (int c = 0; c < 6; ++c) {
      float4 kc = *(const float4*)(k9 + 4 * c);
      s[4*c+0] = fmaf(q8, kc.x, s[4*c+0]);
      s[4*c+1] = fmaf(q8, kc.y, s[4*c+1]);
      s[4*c+2] = fmaf(q8, kc.z, s[4*c+2]);
      s[4*c+3] = fmaf(q8, kc.w, s[4*c+3]);
    }
    s[24] = fmaf(q8, k9[24], s[24]);

    // max: v_max3 tree, 12 ops, dep depth 3
    float t0 = fmaxf(fmaxf(s[0], s[1]), s[2]);
    float t1 = fmaxf(fmaxf(s[3], s[4]), s[5]);
    float t2 = fmaxf(fmaxf(s[6], s[7]), s[8]);
    float t3 = fmaxf(fmaxf(s[9], s[10]), s[11]);
    float t4 = fmaxf(fmaxf(s[12], s[13]), s[14]);
    float t5 = fmaxf(fmaxf(s[15], s[16]), s[17]);
    float t6 = fmaxf(fmaxf(s[18], s[19]), s[20]);
    float t7 = fmaxf(fmaxf(s[21], s[22]), s[23]);
    float u0 = fmaxf(fmaxf(t0, t1), t2);
    float u1 = fmaxf(fmaxf(t3, t4), t5);
    float u2 = fmaxf(fmaxf(t6, t7), s[24]);
    const float m = fmaxf(fmaxf(u0, u1), u2);

    // exp2 + 4-chain sum
    float a0 = 0.f, a1 = 0.f, a2 = 0.f, a3 = 0.f;
#pragma unroll
    for (int j = 0; j < 24; j += 4) {
      float p0 = __builtin_amdgcn_exp2f(s[j + 0] - m);
      float p1 = __builtin_amdgcn_exp2f(s[j + 1] - m);
      float p2 = __builtin_amdgcn_exp2f(s[j + 2] - m);
      float p3 = __builtin_amdgcn_exp2f(s[j + 3] - m);
      s[j + 0] = p0; s[j + 1] = p1; s[j + 2] = p2; s[j + 3] = p3;
      a0 += p0; a1 += p1; a2 += p2; a3 += p3;
    }
    float p24 = __builtin_amdgcn_exp2f(s[24] - m);
    s[24] = p24;
    const float sum = ((a0 + a1) + (a2 + a3)) + p24;
    const float inv = __builtin_amdgcn_rcpf(sum);

    float o[KVD];
#pragma unroll
    for (int d = 0; d < KVD; ++d) o[d] = 0.f;
#pragma unroll
    for (int j = 0; j < NQ; ++j) {
      float4 a = *(const float4*)(vb + j * 8);
      float4 b = *(const float4*)(vb + j * 8 + 4);
      const float p = s[j];
      o[0] = fmaf(p, a.x, o[0]);
      o[1] = fmaf(p, a.y, o[1]);
      o[2] = fmaf(p, a.z, o[2]);
      o[3] = fmaf(p, a.w, o[3]);
      o[4] = fmaf(p, b.x, o[4]);
      o[5] = fmaf(p, b.y, o[5]);
      o[6] = fmaf(p, b.z, o[6]);
      o[7] = fmaf(p, b.w, o[7]);
    }
#pragma unroll
    for (int c = 0; c < 6; ++c) {
      float4 vc = *(const float4*)(v9 + 4 * c);
      o[8] = fmaf(s[4*c+0], vc.x, o[8]);
      o[8] = fmaf(s[4*c+1], vc.y, o[8]);
      o[8] = fmaf(s[4*c+2], vc.z, o[8]);
      o[8] = fmaf(s[4*c+3], vc.w, o[8]);
    }
    o[8] = fmaf(s[24], v9[24], o[8]);

    // residual + one-pass LayerNorm
    float r[KVD];
    float sm = 0.f, sq = 0.f;
#pragma unroll
    for (int d = 0; d < KVD; ++d) {
      r[d] = fmaf(o[d], inv, xv[d]);
      sm += r[d];
      sq = fmaf(r[d], r[d], sq);
    }
    const float mu = sm * (1.0f / 9.0f);
    float var = fmaf(mu, -mu, sq * (1.0f / 9.0f));
    const float rs = __builtin_amdgcn_rsqf(var + 1e-5f);
    float* op = out + item * 225 + tk * KVD;
    // gamma/beta: wave-uniform s_loads, no LDS staging needed
#pragma unroll
    for (int d = 0; d < KVD; ++d)
      op[d] = fmaf((r[d] - mu) * rs, gamma[d], beta[d]);
  }
}

extern "C" void kernel_launch(void* const* d_in, const int* in_sizes, int n_in,
                              void* d_out, int out_size, void* d_ws, size_t ws_size,
                              hipStream_t stream) {
  const float* x     = (const float*)d_in[0];
  const float* mask  = (const float*)d_in[1];
  const float* Wq    = (const float*)d_in[2];
  const float* bq    = (const float*)d_in[3];
  const float* Wk    = (const float*)d_in[4];
  const float* bk    = (const float*)d_in[5];
  const float* Wv    = (const float*)d_in[6];
  const float* bv    = (const float*)d_in[7];
  const float* gamma = (const float*)d_in[8];
  const float* beta  = (const float*)d_in[9];
  float* out = (float*)d_out;
  const int B = in_sizes[0] / 225;
  const int grid = (B + IPB - 1) / IPB;
  attn_fused<<<grid, NT, 0, stream>>>(x, mask, Wq, bq, Wk, bk, Wv, bv,
                                      gamma, beta, out, B);
}